// Round 5
// baseline (128.048 us; speedup 1.0000x reference)
//
#include <hip/hip_runtime.h>

#define BSZ   4
#define TT    6
#define NNODE 400
#define EED   3000
#define DDIM  100
#define NSDIM 30
#define NETYP 10
#define BN    (BSZ*NNODE)                    // 1600
#define NROW  (BSZ*TT*NNODE)                 // 9600
#define NEDGE (BSZ*TT*EED)                   // 72000
#define KPAD  1024

// workspace float offsets
#define OFF_PRE1 0               // 30000
#define OFF_QT   30000           // 3000
#define OFF_BQ   33000           // 100 -> 33104
#define OFF_BF   33104           // 300 -> 33408
#define OFF_WIT  33408           // 30000 -> 63408
#define OFF_BI   63408           // 336
#define OFF_BH   63744           // 336 -> 64080
#define OFF_WFH  64080           // 21504 -> 85584
#define OFF_WFL  85584           // 21504 -> 107088
#define OFF_WOH  107088          // 21504 -> 128592
#define OFF_WOL  128592          // 21504 -> 150096
#define OFF_BWF  150096          // 300000 -> 450096
#define OFF_BWPK 450096          // 172032 -> 622128
#define OFF_WHPK 622128          // 21504 -> 643632
#define OFF_HALL 643632          // 960000 -> 1603632
#define OFF_START 1603632        // 9601 -> pad 1613236
#define OFF_SE   1613236         // 72000 -> 1685236
#define OFF_INV  1685248         // 24 -> pad 1685280
#define OFF_GI   1685280         // 9600*336 = 3225600 -> 4910880

typedef __attribute__((ext_vector_type(8))) short bf16x8;
typedef __attribute__((ext_vector_type(4))) float f32x4;

__device__ __forceinline__ float sigf(float v) { return 1.0f / (1.0f + expf(-v)); }

__device__ __forceinline__ short bfc(float f) {   // f32 -> bf16 bits, RNE
    union { float f; unsigned u; } v; v.f = f;
    unsigned r = v.u + 0x7fffu + ((v.u >> 16) & 1u);
    return (short)(r >> 16);
}

__device__ __forceinline__ float bf2f(short h) {
    union { unsigned u; float f; } x; x.u = ((unsigned)(unsigned short)h) << 16;
    return x.f;
}

__device__ __forceinline__ unsigned cvtpk(float lo, float hi) {
    unsigned r;
    asm("v_cvt_pk_bf16_f32 %0, %1, %2" : "=v"(r) : "v"(lo), "v"(hi));
    return r;
}

// ---------------------------------------------------------------------------
// L1: blocks [0,24): per-(t,b) in-block counting sort of edges by dst row
//     (hist+scan+fill fused, LDS only).
//     blocks [24,626): weight precomputes + inv_nv + gout zero.
__global__ __launch_bounds__(256) void k_front(
    const float* __restrict__ obj_emb, const float* __restrict__ c1_W,
    const float* __restrict__ c1_b, const float* __restrict__ state_W,
    const float* __restrict__ state_b, const float* __restrict__ c2_W,
    const float* __restrict__ c2_b, const float* __restrict__ o_wih,
    const float* __restrict__ o_whh, const float* __restrict__ g_wih,
    const float* __restrict__ g_bih, const float* __restrict__ g_bhh,
    const float* __restrict__ vis, const int* __restrict__ edges,
    float* __restrict__ pre1, float* __restrict__ QT, float* __restrict__ bQ,
    float* __restrict__ bfold, float* __restrict__ WiT,
    float* __restrict__ bI, float* __restrict__ bH,
    ushort* __restrict__ WFH, ushort* __restrict__ WFL,
    ushort* __restrict__ WOH, ushort* __restrict__ WOL,
    float* __restrict__ inv_nv, float* __restrict__ gout,
    int* __restrict__ start, int* __restrict__ sortedE) {
    int tid = threadIdx.x;
    if (blockIdx.x < 24) {                  // bin-sort chunk c = t*4+b
        __shared__ int hcnt[400];
        __shared__ int hstart[400];
        int c = blockIdx.x;
        int t = c >> 2, b = c & 3;
        int febase = (b * TT + t) * EED;
        for (int i = tid; i < 400; i += 256) hcnt[i] = 0;
        __syncthreads();
        for (int i = tid; i < EED; i += 256)
            atomicAdd(&hcnt[edges[(febase + i) * 2 + 1]], 1);
        __syncthreads();
        if (tid < 64) {                     // exclusive prefix scan of 400 bins
            int lane = tid, carry = 0;
            for (int ch = 0; ch < 7; ++ch) {
                int idx = ch * 64 + lane;
                int orig = (idx < 400) ? hcnt[idx] : 0;
                int v = orig;
                #pragma unroll
                for (int off = 1; off < 64; off <<= 1) {
                    int u = __shfl_up(v, off, 64);
                    if (lane >= off) v += u;
                }
                if (idx < 400) hstart[idx] = carry + (v - orig);
                carry += __shfl(v, 63, 64);
            }
        }
        __syncthreads();
        for (int i = tid; i < 400; i += 256) {
            start[c * 400 + i] = c * EED + hstart[i];
            hcnt[i] = hstart[i];            // reuse as cursor
        }
        if (c == 23 && tid == 0) start[NROW] = NEDGE;
        __syncthreads();
        for (int i = tid; i < EED; i += 256) {
            int fe = febase + i;
            int dst = edges[fe * 2 + 1];
            int pos = atomicAdd(&hcnt[dst], 1);
            sortedE[c * EED + pos] = fe;
        }
        return;
    }
    int i = (blockIdx.x - 24) * 256 + tid;
    if (i < 30000) {                        // pre1[cls][d1]
        int cls = i / DDIM, d1 = i % DDIM;
        float acc = 0.f;
        for (int k = 0; k < DDIM; ++k)
            acc += obj_emb[cls * DDIM + k] * c1_W[d1 * 2 * DDIM + k];
        pre1[i] = acc;
    } else if (i < 33000) {                 // QT[s][d1]
        int j = i - 30000, s = j / DDIM, d1 = j % DDIM;
        float acc = 0.f;
        for (int d = 0; d < DDIM; ++d)
            acc += c1_W[d1 * 2 * DDIM + DDIM + d] * state_W[d * NSDIM + s];
        QT[j] = acc;
    } else if (i < 33100) {                 // bQ[d1]
        int d1 = i - 33000;
        float acc = c1_b[d1];
        for (int d = 0; d < DDIM; ++d)
            acc += state_b[d] * c1_W[d1 * 2 * DDIM + DDIM + d];
        bQ[d1] = acc;
    } else if (i < 33400) {                 // bfold[o]
        int o = i - 33100;
        float acc = 0.f;
        for (int d = 0; d < DDIM; ++d)
            acc += o_wih[o * DDIM + d] * c2_b[d];
        bfold[o] = acc;
    } else if (i < 76408) {                 // WFpk hi/lo
        int e = i - 33400;
        int j = e & 7, frag = e >> 3;
        int l = frag & 63, ct = (frag >> 6) % 21, kt = frag / (21 * 64);
        int col = ct * 16 + (l & 15);
        int gate = col / 112, dd = col % 112;
        int k = kt * 32 + ((l >> 4) << 3) + j;
        float v = 0.f;
        if (k < DDIM && dd < DDIM) {
            int o = gate * DDIM + dd;
            for (int d = 0; d < DDIM; ++d)
                v += o_wih[o * DDIM + d] * c2_W[d * DDIM + k];
        }
        short hi = bfc(v);
        WFH[frag * 8 + j] = (ushort)hi;
        WFL[frag * 8 + j] = (ushort)bfc(v - bf2f(hi));
    } else if (i < 119416) {                // WOpk hi/lo = o_whh^T
        int e = i - 76408;
        int j = e & 7, frag = e >> 3;
        int l = frag & 63, ct = (frag >> 6) % 21, kt = frag / (21 * 64);
        int col = ct * 16 + (l & 15);
        int gate = col / 112, dd = col % 112;
        int k = kt * 32 + ((l >> 4) << 3) + j;
        float v = 0.f;
        if (k < DDIM && dd < DDIM)
            v = o_whh[(gate * DDIM + dd) * DDIM + k];
        short hi = bfc(v);
        WOH[frag * 8 + j] = (ushort)hi;
        WOL[frag * 8 + j] = (ushort)bfc(v - bf2f(hi));
    } else if (i < 149416) {                // WiT[j][go] = g_wih^T
        int j = i - 119416, k = j / 300, o = j % 300;
        WiT[j] = g_wih[o * DDIM + k];
    } else if (i < 149752) {                // bI[col]
        int col = i - 149416, gate = col / 112, o = col % 112;
        bI[col] = (o < DDIM) ? g_bih[gate * DDIM + o] : 0.f;
    } else if (i < 150088) {                // bH[col]
        int col = i - 149752, gate = col / 112, o = col % 112;
        bH[col] = (o < DDIM) ? g_bhh[gate * DDIM + o] : 0.f;
    } else if (i >= 150144 && i < 151680) { // inv_nv[bt]
        int g = (i - 150144) >> 6;
        int lane = i & 63;
        float s = 0.f;
        for (int n = lane; n < NNODE; n += 64)
            s += vis[g * NNODE + n];
        #pragma unroll
        for (int off = 32; off > 0; off >>= 1)
            s += __shfl_down(s, off, 64);
        if (lane == 0) inv_nv[g] = 1.f / (s + 1e-9f);
    } else if (i >= 151680 && i < 154080) { // zero gout
        gout[i - 151680] = 0.f;
    }
}

// ---------------------------------------------------------------------------
// L2: BW_f32 (blocks [0,670)) + GI via split-bf16 MFMA (blocks [670,1270)).
__global__ __launch_bounds__(448) void k_mid(
    const float* __restrict__ edge_embed, const float* __restrict__ WiT,
    float* __restrict__ BW,
    const int* __restrict__ cls, const float* __restrict__ states,
    const float* __restrict__ pre1, const float* __restrict__ QT,
    const float* __restrict__ bQ, const float* __restrict__ bfold,
    const bf16x8* __restrict__ WFH, const bf16x8* __restrict__ WFL,
    float* __restrict__ GI) {
    __shared__ float st_lds[16 * NSDIM];
    __shared__ float hid_lds[16 * 112];
    __shared__ int cls_lds[16];
    int tid = threadIdx.x;
    if (blockIdx.x < 670) {                 // BW[kk][go]
        int i = blockIdx.x * 448 + tid;
        if (i < 1000 * 300) {
            int kk = i / 300, go = i % 300;
            int g = kk / DDIM, k = kk % DDIM;
            const float* es = edge_embed + g * DDIM * DDIM + k;
            float acc = 0.f;
            for (int j = 0; j < DDIM; ++j)
                acc += es[j * DDIM] * WiT[j * 300 + go];
            BW[i] = acc;
        }
        return;
    }
    // GI: hid = relu(pre1+states@Q^T+bQ); GI = hid @ WF + bfold (MFMA)
    int r0 = (blockIdx.x - 670) * 16;
    for (int idx = tid; idx < 16 * NSDIM; idx += 448) st_lds[idx] = states[r0 * NSDIM + idx];
    if (tid < 16) cls_lds[tid] = cls[r0 + tid];
    __syncthreads();
    #pragma unroll
    for (int u = 0; u < 4; ++u) {
        int it = tid + u * 448;
        if (it < 1600) {
            int n = it / 100, d = it % 100;
            float acc = bQ[d] + pre1[cls_lds[n] * DDIM + d];
            for (int s = 0; s < NSDIM; ++s)
                acc += QT[s * DDIM + d] * st_lds[n * NSDIM + s];
            hid_lds[n * 112 + d] = fmaxf(acc, 0.f);
        }
    }
    __syncthreads();
    int w = tid >> 6, l = tid & 63, rit = l & 15, kgrp = l >> 4;
    f32x4 acc3[3];
    acc3[0] = acc3[1] = acc3[2] = (f32x4){0.f, 0.f, 0.f, 0.f};
    for (int kt = 0; kt < 4; ++kt) {
        bf16x8 Ahi, Alo;
        #pragma unroll
        for (int j = 0; j < 8; ++j) {
            int k = kt * 32 + kgrp * 8 + j;
            float v = (k < DDIM) ? hid_lds[rit * 112 + k] : 0.f;
            short hi = bfc(v);
            Ahi[j] = hi;
            Alo[j] = bfc(v - bf2f(hi));
        }
        #pragma unroll
        for (int p = 0; p < 3; ++p) {
            int ct = w + p * 7;
            bf16x8 Bhi = WFH[(kt * 21 + ct) * 64 + l];
            bf16x8 Blo = WFL[(kt * 21 + ct) * 64 + l];
            acc3[p] = __builtin_amdgcn_mfma_f32_16x16x32_bf16(Ahi, Bhi, acc3[p], 0, 0, 0);
            acc3[p] = __builtin_amdgcn_mfma_f32_16x16x32_bf16(Alo, Bhi, acc3[p], 0, 0, 0);
            acc3[p] = __builtin_amdgcn_mfma_f32_16x16x32_bf16(Ahi, Blo, acc3[p], 0, 0, 0);
        }
    }
    int dd = w * 16 + rit;
    if (dd < DDIM) {
        int b = r0 / (TT * NNODE), t = (r0 / NNODE) % TT, nn0 = r0 % NNODE;
        int trow0 = t * BN + b * NNODE + nn0;
        #pragma unroll
        for (int p = 0; p < 3; ++p) {
            float bias = bfold[p * DDIM + dd];
            #pragma unroll
            for (int j = 0; j < 4; ++j) {
                int row = kgrp * 4 + j;
                GI[(trow0 + row) * 336 + p * 112 + dd] = acc3[p][j] + bias;
            }
        }
    }
}

// ---------------------------------------------------------------------------
// L3: outer temporal GRU via split-bf16 MFMA (blocks [0,100))
//   + bf16 pack of BW/Wh (blocks [100,208)).
__global__ __launch_bounds__(448) void k_mid2(const float* __restrict__ GI,
    const bf16x8* __restrict__ WOH, const bf16x8* __restrict__ WOL,
    float* __restrict__ Hall,
    const float* __restrict__ BW, const float* __restrict__ g_whh,
    bf16x8* __restrict__ BWpk, bf16x8* __restrict__ WHpk) {
    __shared__ float h_lds[16 * 112];
    int tid = threadIdx.x;
    if (blockIdx.x >= 100) {                // pack BW (K=1024) and Wh (K=128)
        int i = (blockIdx.x - 100) * 448 + tid;
        if (i < 43008) {
            int l = i & 63, c = (i >> 6) % 21, kt = i / (21 * 64);
            int col = c * 16 + (l & 15);
            int gate = col / 112, o = col % 112;
            bf16x8 r;
            #pragma unroll
            for (int j = 0; j < 8; ++j) {
                int kk = kt * 32 + ((l >> 4) << 3) + j;
                float v = (kk < 1000 && o < DDIM) ? BW[kk * 300 + gate * DDIM + o] : 0.f;
                r[j] = bfc(v);
            }
            BWpk[i] = r;
        } else if (i < 48384) {
            int id = i - 43008;
            int l = id & 63, c = (id >> 6) % 21, kt2 = id / (21 * 64);
            int col = c * 16 + (l & 15);
            int gate = col / 112, o = col % 112;
            bf16x8 r;
            #pragma unroll
            for (int j = 0; j < 8; ++j) {
                int k = kt2 * 32 + ((l >> 4) << 3) + j;
                float v = (k < DDIM && o < DDIM) ? g_whh[(gate * DDIM + o) * DDIM + k] : 0.f;
                r[j] = bfc(v);
            }
            WHpk[id] = r;
        }
        return;
    }
    // temporal GRU: 16 nodes/block
    int bn0 = blockIdx.x * 16;
    for (int idx = tid; idx < 16 * 112; idx += 448) h_lds[idx] = 0.f;
    __syncthreads();
    int w = tid >> 6, l = tid & 63, rit = l & 15, kgrp = l >> 4;
    int dd = w * 16 + rit;
    for (int t = 0; t < TT; ++t) {
        float gir[4], giz[4], gin[4], hold[4];
        if (dd < DDIM) {
            #pragma unroll
            for (int j = 0; j < 4; ++j) {
                int node = kgrp * 4 + j;
                int trow = t * BN + bn0 + node;
                gir[j] = GI[trow * 336 + dd];
                giz[j] = GI[trow * 336 + 112 + dd];
                gin[j] = GI[trow * 336 + 224 + dd];
                hold[j] = h_lds[node * 112 + dd];
            }
        }
        f32x4 a0 = (f32x4){0.f, 0.f, 0.f, 0.f};
        f32x4 a1 = (f32x4){0.f, 0.f, 0.f, 0.f};
        f32x4 a2 = (f32x4){0.f, 0.f, 0.f, 0.f};
        if (t > 0) {
            for (int kt = 0; kt < 4; ++kt) {
                bf16x8 Ahi, Alo;
                #pragma unroll
                for (int j = 0; j < 8; ++j) {
                    int k = kt * 32 + kgrp * 8 + j;
                    float v = (k < DDIM) ? h_lds[rit * 112 + k] : 0.f;
                    short hi = bfc(v);
                    Ahi[j] = hi;
                    Alo[j] = bfc(v - bf2f(hi));
                }
                {
                    bf16x8 Bhi = WOH[(kt * 21 + w) * 64 + l];
                    bf16x8 Blo = WOL[(kt * 21 + w) * 64 + l];
                    a0 = __builtin_amdgcn_mfma_f32_16x16x32_bf16(Ahi, Bhi, a0, 0, 0, 0);
                    a0 = __builtin_amdgcn_mfma_f32_16x16x32_bf16(Alo, Bhi, a0, 0, 0, 0);
                    a0 = __builtin_amdgcn_mfma_f32_16x16x32_bf16(Ahi, Blo, a0, 0, 0, 0);
                }
                {
                    bf16x8 Bhi = WOH[(kt * 21 + w + 7) * 64 + l];
                    bf16x8 Blo = WOL[(kt * 21 + w + 7) * 64 + l];
                    a1 = __builtin_amdgcn_mfma_f32_16x16x32_bf16(Ahi, Bhi, a1, 0, 0, 0);
                    a1 = __builtin_amdgcn_mfma_f32_16x16x32_bf16(Alo, Bhi, a1, 0, 0, 0);
                    a1 = __builtin_amdgcn_mfma_f32_16x16x32_bf16(Ahi, Blo, a1, 0, 0, 0);
                }
                {
                    bf16x8 Bhi = WOH[(kt * 21 + w + 14) * 64 + l];
                    bf16x8 Blo = WOL[(kt * 21 + w + 14) * 64 + l];
                    a2 = __builtin_amdgcn_mfma_f32_16x16x32_bf16(Ahi, Bhi, a2, 0, 0, 0);
                    a2 = __builtin_amdgcn_mfma_f32_16x16x32_bf16(Alo, Bhi, a2, 0, 0, 0);
                    a2 = __builtin_amdgcn_mfma_f32_16x16x32_bf16(Ahi, Blo, a2, 0, 0, 0);
                }
            }
        }
        __syncthreads();
        if (dd < DDIM) {
            #pragma unroll
            for (int j = 0; j < 4; ++j) {
                int node = kgrp * 4 + j;
                int trow = t * BN + bn0 + node;
                float r = sigf(gir[j] + a0[j]);
                float z = sigf(giz[j] + a1[j]);
                float nn = tanhf(gin[j] + r * a2[j]);
                float hnew = (1.f - z) * nn + z * hold[j];
                h_lds[node * 112 + dd] = hnew;
                Hall[trow * DDIM + dd] = hnew;
            }
        }
        __syncthreads();
    }
}

// ---------------------------------------------------------------------------
// L4: fused gather + inner GRU, 32 rows/block. Gather accumulates each row
// in registers (lane l owns slot pairs {128j+2l,+1}) and writes bf16 straight
// into the XOR-swizzled LDS layout the MFMA reads. No U in HBM.
template<int G>
__device__ __forceinline__ void gacc2(float* acc, const float* __restrict__ hs,
                                      float m, int l) {
    constexpr int k0 = 100 * G, k1 = k0 + 100;
    constexpr int J0 = k0 >> 7, J1 = (k1 - 1) >> 7;
    #pragma unroll
    for (int j = J0; j <= J1; ++j) {
        int s = 128 * j + 2 * l;
        if (s >= k0 && s < k1) {
            float2 hv = *(const float2*)(hs + (s - k0));
            acc[2 * j]     += m * hv.x;
            acc[2 * j + 1] += m * hv.y;
        }
    }
}

__global__ __launch_bounds__(448) void k_fused32(
    const int* __restrict__ edges, const int* __restrict__ etype,
    const float* __restrict__ emask, const int* __restrict__ start,
    const int* __restrict__ sortedE,
    const bf16x8* __restrict__ BWpk, const bf16x8* __restrict__ WHpk,
    const float* __restrict__ bI, const float* __restrict__ bH,
    const float* __restrict__ Hall, const float* __restrict__ visv,
    const float* __restrict__ inv_nv, float* __restrict__ out,
    float* __restrict__ gout) {
    __shared__ unsigned lds[16384];          // 32 rows x 512 words
    int tid = threadIdx.x;
    int w = tid >> 6, l = tid & 63;
    int rit = l & 15, kgrp = l >> 4;
    int rbase = blockIdx.x * 32;

    // ---- gather phase: wave w handles rows w, w+7, ... of the 32 ----
    for (int r = w; r < 32; r += 7) {
        int trd = rbase + r;
        int s0 = start[trd], s1 = start[trd + 1];
        int rowbase = (trd / NNODE) * NNODE;
        float acc[16];
        #pragma unroll
        for (int j = 0; j < 16; ++j) acc[j] = 0.f;
        for (int e = s0; e < s1; ++e) {
            int fe = sortedE[e];
            float m = emask[fe];
            int src = edges[fe * 2 + 0];
            int g = etype[fe];
            const float* hs = Hall + (size_t)(rowbase + src) * DDIM;
            switch (g) {
                case 0: gacc2<0>(acc, hs, m, l); break;
                case 1: gacc2<1>(acc, hs, m, l); break;
                case 2: gacc2<2>(acc, hs, m, l); break;
                case 3: gacc2<3>(acc, hs, m, l); break;
                case 4: gacc2<4>(acc, hs, m, l); break;
                case 5: gacc2<5>(acc, hs, m, l); break;
                case 6: gacc2<6>(acc, hs, m, l); break;
                case 7: gacc2<7>(acc, hs, m, l); break;
                case 8: gacc2<8>(acc, hs, m, l); break;
                case 9: gacc2<9>(acc, hs, m, l); break;
            }
        }
        #pragma unroll
        for (int j = 0; j < 8; ++j) {        // word 64j+l = slots (128j+2l, +1)
            unsigned word = cvtpk(acc[2 * j], acc[2 * j + 1]);
            int g16 = 16 * j + (l >> 2);
            int wd = r * 512 + ((g16 * 4) ^ ((r & 7) << 2)) + (l & 3);
            lds[wd] = word;
        }
    }
    __syncthreads();

    f32x4 acc[2][3];
    #pragma unroll
    for (int mt = 0; mt < 2; ++mt)
        #pragma unroll
        for (int q = 0; q < 3; ++q) acc[mt][q] = (f32x4){0.f, 0.f, 0.f, 0.f};

    for (int kt = 0; kt < 32; ++kt) {        // gi = U @ BW (K=1024)
        bf16x8 fb0 = BWpk[(kt * 21 + w) * 64 + l];
        bf16x8 fb1 = BWpk[(kt * 21 + w + 7) * 64 + l];
        bf16x8 fb2 = BWpk[(kt * 21 + w + 14) * 64 + l];
        #pragma unroll
        for (int mt = 0; mt < 2; ++mt) {
            int row = mt * 16 + rit;
            int wd = row * 512 + (((kt * 16 + kgrp * 4)) ^ ((row & 7) << 2));
            bf16x8 fa = *(bf16x8*)&lds[wd];
            acc[mt][0] = __builtin_amdgcn_mfma_f32_16x16x32_bf16(fa, fb0, acc[mt][0], 0, 0, 0);
            acc[mt][1] = __builtin_amdgcn_mfma_f32_16x16x32_bf16(fa, fb1, acc[mt][1], 0, 0, 0);
            acc[mt][2] = __builtin_amdgcn_mfma_f32_16x16x32_bf16(fa, fb2, acc[mt][2], 0, 0, 0);
        }
    }
    __syncthreads();

    for (int i = tid; i < 512; i += 448) {   // restage Hall (bf16, K pad 128)
        int row = i >> 4, g16 = i & 15;
        int k0 = g16 * 8;
        const float* hs = Hall + (size_t)(rbase + row) * DDIM;
        float v[8];
        #pragma unroll
        for (int jj = 0; jj < 8; ++jj)
            v[jj] = (k0 + jj < DDIM) ? hs[k0 + jj] : 0.f;
        int4 wv;
        wv.x = (int)cvtpk(v[0], v[1]);
        wv.y = (int)cvtpk(v[2], v[3]);
        wv.z = (int)cvtpk(v[4], v[5]);
        wv.w = (int)cvtpk(v[6], v[7]);
        int wd = row * 64 + ((g16 * 4) ^ ((row & 7) << 2));
        *(int4*)&lds[wd] = wv;
    }
    __syncthreads();

    f32x4 hacc[2];
    hacc[0] = (f32x4){0.f, 0.f, 0.f, 0.f};
    hacc[1] = (f32x4){0.f, 0.f, 0.f, 0.f};
    for (int kt2 = 0; kt2 < 4; ++kt2) {
        bf16x8 fb0 = WHpk[(kt2 * 21 + w) * 64 + l];
        bf16x8 fb1 = WHpk[(kt2 * 21 + w + 7) * 64 + l];
        bf16x8 fb2 = WHpk[(kt2 * 21 + w + 14) * 64 + l];
        #pragma unroll
        for (int mt = 0; mt < 2; ++mt) {
            int row = mt * 16 + rit;
            int wd = row * 64 + (((kt2 * 16 + kgrp * 4)) ^ ((row & 7) << 2));
            bf16x8 fh = *(bf16x8*)&lds[wd];
            acc[mt][0] = __builtin_amdgcn_mfma_f32_16x16x32_bf16(fh, fb0, acc[mt][0], 0, 0, 0);
            acc[mt][1] = __builtin_amdgcn_mfma_f32_16x16x32_bf16(fh, fb1, acc[mt][1], 0, 0, 0);
            hacc[mt]  = __builtin_amdgcn_mfma_f32_16x16x32_bf16(fh, fb2, hacc[mt], 0, 0, 0);
        }
    }

    int col = w * 16 + rit;
    if (col < DDIM) {
        float bIr = bI[col], bIz = bI[112 + col], bIn = bI[224 + col];
        float bHr = bH[col], bHz = bH[112 + col], bHn = bH[224 + col];
        int t = rbase / BN;
        #pragma unroll
        for (int mt = 0; mt < 2; ++mt) {
            int r2 = (rbase + mt * 16) % BN;
            int b = r2 / NNODE, n0 = r2 % NNODE;
            int bt = b * TT + t;
            int trow0 = rbase + mt * 16 + kgrp * 4;
            int brow0 = bt * NNODE + n0 + kgrp * 4;
            float gs = 0.f;
            #pragma unroll
            for (int j = 0; j < 4; ++j) {
                float r = sigf(acc[mt][0][j] + bIr + bHr);
                float z = sigf(acc[mt][1][j] + bIz + bHz);
                float ghn = hacc[mt][j] + bHn;
                float nn = tanhf(acc[mt][2][j] + bIn + r * ghn);
                float hold = Hall[(trow0 + j) * DDIM + col];
                float feat = (1.f - z) * nn + z * hold;
                int brow = brow0 + j;
                float v = visv[brow];
                float outv = feat * v;
                out[brow * DDIM + col] = outv;
                gs += outv * v;              // reference applies vis twice in mean
            }
            gs += __shfl_xor(gs, 16, 64);
            gs += __shfl_xor(gs, 32, 64);
            if (kgrp == 0)
                atomicAdd(&gout[bt * DDIM + col], gs * inv_nv[bt]);
        }
    }
}

// ---------------------------------------------------------------------------
extern "C" void kernel_launch(void* const* d_in, const int* in_sizes, int n_in,
                              void* d_out, int out_size, void* d_ws, size_t ws_size,
                              hipStream_t stream) {
    const int*   class_names = (const int*)d_in[0];
    const float* states      = (const float*)d_in[1];
    const int*   edges       = (const int*)d_in[2];
    const int*   edge_types  = (const int*)d_in[3];
    const float* visibility  = (const float*)d_in[4];
    const float* mask_edges  = (const float*)d_in[5];
    const float* obj_emb     = (const float*)d_in[6];
    const float* state_W     = (const float*)d_in[7];
    const float* state_b     = (const float*)d_in[8];
    const float* c1_W        = (const float*)d_in[9];
    const float* c1_b        = (const float*)d_in[10];
    const float* c2_W        = (const float*)d_in[11];
    const float* c2_b        = (const float*)d_in[12];
    const float* edge_embed  = (const float*)d_in[13];
    const float* g_wih       = (const float*)d_in[14];
    const float* g_whh       = (const float*)d_in[15];
    const float* g_bih       = (const float*)d_in[16];
    const float* g_bhh       = (const float*)d_in[17];
    const float* o_wih       = (const float*)d_in[18];
    const float* o_whh       = (const float*)d_in[19];

    float* out = (float*)d_out;
    float* gout = out + (size_t)NROW * DDIM;
    float* ws  = (float*)d_ws;
    float*  pre1  = ws + OFF_PRE1;
    float*  QT    = ws + OFF_QT;
    float*  bQ    = ws + OFF_BQ;
    float*  bfold = ws + OFF_BF;
    float*  WiT   = ws + OFF_WIT;
    float*  bI    = ws + OFF_BI;
    float*  bH    = ws + OFF_BH;
    ushort* WFH   = (ushort*)(ws + OFF_WFH);
    ushort* WFL   = (ushort*)(ws + OFF_WFL);
    ushort* WOH   = (ushort*)(ws + OFF_WOH);
    ushort* WOL   = (ushort*)(ws + OFF_WOL);
    float*  BWf   = ws + OFF_BWF;
    bf16x8* BWpk  = (bf16x8*)(ws + OFF_BWPK);
    bf16x8* WHpk  = (bf16x8*)(ws + OFF_WHPK);
    float*  Hall  = ws + OFF_HALL;
    int*    start = (int*)(ws + OFF_START);
    int*    sortedE = (int*)(ws + OFF_SE);
    float*  inv_nv= ws + OFF_INV;
    float*  GI    = ws + OFF_GI;

    // L1: prep + packs + inv_nv + zero(gout) + per-chunk edge bin-sort
    k_front<<<626, 256, 0, stream>>>(obj_emb, c1_W, c1_b, state_W, state_b,
                                     c2_W, c2_b, o_wih, o_whh, g_wih, g_bih, g_bhh,
                                     visibility, edges, pre1, QT, bQ, bfold, WiT,
                                     bI, bH, WFH, WFL, WOH, WOL, inv_nv, gout,
                                     start, sortedE);
    // L2: BW_f32 + GI (MFMA)
    k_mid<<<1270, 448, 0, stream>>>(edge_embed, WiT, BWf, class_names, states,
                                    pre1, QT, bQ, bfold,
                                    (const bf16x8*)WFH, (const bf16x8*)WFL, GI);
    // L3: outer GRU (MFMA) + bf16 pack
    k_mid2<<<208, 448, 0, stream>>>(GI, (const bf16x8*)WOH, (const bf16x8*)WOL,
                                    Hall, BWf, g_whh, BWpk, WHpk);
    // L4: fused gather + inner GRU + visibility mask + global mean
    k_fused32<<<NROW / 32, 448, 0, stream>>>(edges, edge_types, mask_edges,
                                             start, sortedE, BWpk, WHpk, bI, bH,
                                             Hall, visibility, inv_nv, out, gout);
}

// Round 6
// 118.066 us; speedup vs baseline: 1.0845x; 1.0845x over previous
//
#include <hip/hip_runtime.h>

#define BSZ   4
#define TT    6
#define NNODE 400
#define EED   3000
#define DDIM  100
#define NSDIM 30
#define NETYP 10
#define BN    (BSZ*NNODE)                    // 1600
#define NROW  (BSZ*TT*NNODE)                 // 9600
#define NEDGE (BSZ*TT*EED)                   // 72000
#define KPAD  1024

// workspace float offsets
#define OFF_PRE1 0               // 30000
#define OFF_QT   30000           // 3000
#define OFF_BQ   33000           // 100 -> 33104
#define OFF_BF   33104           // 300 -> 33408
#define OFF_WIT  33408           // 30000 -> 63408
#define OFF_BI   63408           // 336
#define OFF_BH   63744           // 336 -> 64080
#define OFF_WFH  64080           // 21504 -> 85584
#define OFF_WFL  85584           // 21504 -> 107088
#define OFF_WOH  107088          // 21504 -> 128592
#define OFF_WOL  128592          // 21504 -> 150096
#define OFF_BWF  150096          // 300000 -> 450096
#define OFF_BWPK 450096          // 172032 -> 622128
#define OFF_WHPK 622128          // 21504 -> 643632
#define OFF_HALL 643632          // 960000 -> 1603632
#define OFF_START 1603632        // 9601 -> pad 1613236
#define OFF_SE   1613236         // 72000 int2 = 144000 -> 1757236
#define OFF_INV  1757248         // 24 -> pad 1757280
#define OFF_GI   1757280         // 9600*336 = 3225600 -> 4982880

typedef __attribute__((ext_vector_type(8))) short bf16x8;
typedef __attribute__((ext_vector_type(4))) float f32x4;

__device__ __forceinline__ float sigf(float v) { return 1.0f / (1.0f + expf(-v)); }

__device__ __forceinline__ short bfc(float f) {   // f32 -> bf16 bits, RNE
    union { float f; unsigned u; } v; v.f = f;
    unsigned r = v.u + 0x7fffu + ((v.u >> 16) & 1u);
    return (short)(r >> 16);
}

__device__ __forceinline__ float bf2f(short h) {
    union { unsigned u; float f; } x; x.u = ((unsigned)(unsigned short)h) << 16;
    return x.f;
}

__device__ __forceinline__ unsigned cvtpk(float lo, float hi) {
    unsigned r;
    asm("v_cvt_pk_bf16_f32 %0, %1, %2" : "=v"(r) : "v"(lo), "v"(hi));
    return r;
}

// ---------------------------------------------------------------------------
// L1: blocks [0,24): per-(t,b) in-block counting sort of edges by dst row;
//     sorted records packed {src|g<<16, m} to kill one load-dependency level.
//     blocks [24,626): weight precomputes + inv_nv + gout zero.
__global__ __launch_bounds__(256) void k_front(
    const float* __restrict__ obj_emb, const float* __restrict__ c1_W,
    const float* __restrict__ c1_b, const float* __restrict__ state_W,
    const float* __restrict__ state_b, const float* __restrict__ c2_W,
    const float* __restrict__ c2_b, const float* __restrict__ o_wih,
    const float* __restrict__ o_whh, const float* __restrict__ g_wih,
    const float* __restrict__ g_bih, const float* __restrict__ g_bhh,
    const float* __restrict__ vis, const int* __restrict__ edges,
    const int* __restrict__ etype, const float* __restrict__ emask,
    float* __restrict__ pre1, float* __restrict__ QT, float* __restrict__ bQ,
    float* __restrict__ bfold, float* __restrict__ WiT,
    float* __restrict__ bI, float* __restrict__ bH,
    ushort* __restrict__ WFH, ushort* __restrict__ WFL,
    ushort* __restrict__ WOH, ushort* __restrict__ WOL,
    float* __restrict__ inv_nv, float* __restrict__ gout,
    int* __restrict__ start, int2* __restrict__ sortedE2) {
    int tid = threadIdx.x;
    if (blockIdx.x < 24) {                  // bin-sort chunk c = t*4+b
        __shared__ int hcnt[400];
        __shared__ int hstart[400];
        int c = blockIdx.x;
        int t = c >> 2, b = c & 3;
        int febase = (b * TT + t) * EED;
        for (int i = tid; i < 400; i += 256) hcnt[i] = 0;
        __syncthreads();
        for (int i = tid; i < EED; i += 256)
            atomicAdd(&hcnt[edges[(febase + i) * 2 + 1]], 1);
        __syncthreads();
        if (tid < 64) {                     // exclusive prefix scan of 400 bins
            int lane = tid, carry = 0;
            for (int ch = 0; ch < 7; ++ch) {
                int idx = ch * 64 + lane;
                int orig = (idx < 400) ? hcnt[idx] : 0;
                int v = orig;
                #pragma unroll
                for (int off = 1; off < 64; off <<= 1) {
                    int u = __shfl_up(v, off, 64);
                    if (lane >= off) v += u;
                }
                if (idx < 400) hstart[idx] = carry + (v - orig);
                carry += __shfl(v, 63, 64);
            }
        }
        __syncthreads();
        for (int i = tid; i < 400; i += 256) {
            start[c * 400 + i] = c * EED + hstart[i];
            hcnt[i] = hstart[i];            // reuse as cursor
        }
        if (c == 23 && tid == 0) start[NROW] = NEDGE;
        __syncthreads();
        for (int i = tid; i < EED; i += 256) {
            int fe = febase + i;
            int2 ed = *(const int2*)(edges + fe * 2);   // (src,dst)
            int pos = atomicAdd(&hcnt[ed.y], 1);
            int g = etype[fe];
            float m = emask[fe];
            sortedE2[c * EED + pos] = make_int2(ed.x | (g << 16), __float_as_int(m));
        }
        return;
    }
    int i = (blockIdx.x - 24) * 256 + tid;
    if (i < 30000) {                        // pre1[cls][d1]
        int cls = i / DDIM, d1 = i % DDIM;
        float acc = 0.f;
        for (int k = 0; k < DDIM; ++k)
            acc += obj_emb[cls * DDIM + k] * c1_W[d1 * 2 * DDIM + k];
        pre1[i] = acc;
    } else if (i < 33000) {                 // QT[s][d1]
        int j = i - 30000, s = j / DDIM, d1 = j % DDIM;
        float acc = 0.f;
        for (int d = 0; d < DDIM; ++d)
            acc += c1_W[d1 * 2 * DDIM + DDIM + d] * state_W[d * NSDIM + s];
        QT[j] = acc;
    } else if (i < 33100) {                 // bQ[d1]
        int d1 = i - 33000;
        float acc = c1_b[d1];
        for (int d = 0; d < DDIM; ++d)
            acc += state_b[d] * c1_W[d1 * 2 * DDIM + DDIM + d];
        bQ[d1] = acc;
    } else if (i < 33400) {                 // bfold[o]
        int o = i - 33100;
        float acc = 0.f;
        for (int d = 0; d < DDIM; ++d)
            acc += o_wih[o * DDIM + d] * c2_b[d];
        bfold[o] = acc;
    } else if (i < 76408) {                 // WFpk hi/lo
        int e = i - 33400;
        int j = e & 7, frag = e >> 3;
        int l = frag & 63, ct = (frag >> 6) % 21, kt = frag / (21 * 64);
        int col = ct * 16 + (l & 15);
        int gate = col / 112, dd = col % 112;
        int k = kt * 32 + ((l >> 4) << 3) + j;
        float v = 0.f;
        if (k < DDIM && dd < DDIM) {
            int o = gate * DDIM + dd;
            for (int d = 0; d < DDIM; ++d)
                v += o_wih[o * DDIM + d] * c2_W[d * DDIM + k];
        }
        short hi = bfc(v);
        WFH[frag * 8 + j] = (ushort)hi;
        WFL[frag * 8 + j] = (ushort)bfc(v - bf2f(hi));
    } else if (i < 119416) {                // WOpk hi/lo = o_whh^T
        int e = i - 76408;
        int j = e & 7, frag = e >> 3;
        int l = frag & 63, ct = (frag >> 6) % 21, kt = frag / (21 * 64);
        int col = ct * 16 + (l & 15);
        int gate = col / 112, dd = col % 112;
        int k = kt * 32 + ((l >> 4) << 3) + j;
        float v = 0.f;
        if (k < DDIM && dd < DDIM)
            v = o_whh[(gate * DDIM + dd) * DDIM + k];
        short hi = bfc(v);
        WOH[frag * 8 + j] = (ushort)hi;
        WOL[frag * 8 + j] = (ushort)bfc(v - bf2f(hi));
    } else if (i < 149416) {                // WiT[j][go] = g_wih^T
        int j = i - 119416, k = j / 300, o = j % 300;
        WiT[j] = g_wih[o * DDIM + k];
    } else if (i < 149752) {                // bI[col]
        int col = i - 149416, gate = col / 112, o = col % 112;
        bI[col] = (o < DDIM) ? g_bih[gate * DDIM + o] : 0.f;
    } else if (i < 150088) {                // bH[col]
        int col = i - 149752, gate = col / 112, o = col % 112;
        bH[col] = (o < DDIM) ? g_bhh[gate * DDIM + o] : 0.f;
    } else if (i >= 150144 && i < 151680) { // inv_nv[bt]
        int g = (i - 150144) >> 6;
        int lane = i & 63;
        float s = 0.f;
        for (int n = lane; n < NNODE; n += 64)
            s += vis[g * NNODE + n];
        #pragma unroll
        for (int off = 32; off > 0; off >>= 1)
            s += __shfl_down(s, off, 64);
        if (lane == 0) inv_nv[g] = 1.f / (s + 1e-9f);
    } else if (i >= 151680 && i < 154080) { // zero gout
        gout[i - 151680] = 0.f;
    }
}

// ---------------------------------------------------------------------------
// L2: BW_f32 (blocks [0,670)) + GI via split-bf16 MFMA (blocks [670,1270)).
__global__ __launch_bounds__(448) void k_mid(
    const float* __restrict__ edge_embed, const float* __restrict__ WiT,
    float* __restrict__ BW,
    const int* __restrict__ cls, const float* __restrict__ states,
    const float* __restrict__ pre1, const float* __restrict__ QT,
    const float* __restrict__ bQ, const float* __restrict__ bfold,
    const bf16x8* __restrict__ WFH, const bf16x8* __restrict__ WFL,
    float* __restrict__ GI) {
    __shared__ float st_lds[16 * NSDIM];
    __shared__ float hid_lds[16 * 112];
    __shared__ int cls_lds[16];
    int tid = threadIdx.x;
    if (blockIdx.x < 670) {                 // BW[kk][go]
        int i = blockIdx.x * 448 + tid;
        if (i < 1000 * 300) {
            int kk = i / 300, go = i % 300;
            int g = kk / DDIM, k = kk % DDIM;
            const float* es = edge_embed + g * DDIM * DDIM + k;
            float acc = 0.f;
            for (int j = 0; j < DDIM; ++j)
                acc += es[j * DDIM] * WiT[j * 300 + go];
            BW[i] = acc;
        }
        return;
    }
    // GI: hid = relu(pre1+states@Q^T+bQ); GI = hid @ WF + bfold (MFMA)
    int r0 = (blockIdx.x - 670) * 16;
    for (int idx = tid; idx < 16 * NSDIM; idx += 448) st_lds[idx] = states[r0 * NSDIM + idx];
    if (tid < 16) cls_lds[tid] = cls[r0 + tid];
    __syncthreads();
    #pragma unroll
    for (int u = 0; u < 4; ++u) {
        int it = tid + u * 448;
        if (it < 1600) {
            int n = it / 100, d = it % 100;
            float acc = bQ[d] + pre1[cls_lds[n] * DDIM + d];
            for (int s = 0; s < NSDIM; ++s)
                acc += QT[s * DDIM + d] * st_lds[n * NSDIM + s];
            hid_lds[n * 112 + d] = fmaxf(acc, 0.f);
        }
    }
    __syncthreads();
    int w = tid >> 6, l = tid & 63, rit = l & 15, kgrp = l >> 4;
    f32x4 acc3[3];
    acc3[0] = acc3[1] = acc3[2] = (f32x4){0.f, 0.f, 0.f, 0.f};
    for (int kt = 0; kt < 4; ++kt) {
        bf16x8 Ahi, Alo;
        #pragma unroll
        for (int j = 0; j < 8; ++j) {
            int k = kt * 32 + kgrp * 8 + j;
            float v = (k < DDIM) ? hid_lds[rit * 112 + k] : 0.f;
            short hi = bfc(v);
            Ahi[j] = hi;
            Alo[j] = bfc(v - bf2f(hi));
        }
        #pragma unroll
        for (int p = 0; p < 3; ++p) {
            int ct = w + p * 7;
            bf16x8 Bhi = WFH[(kt * 21 + ct) * 64 + l];
            bf16x8 Blo = WFL[(kt * 21 + ct) * 64 + l];
            acc3[p] = __builtin_amdgcn_mfma_f32_16x16x32_bf16(Ahi, Bhi, acc3[p], 0, 0, 0);
            acc3[p] = __builtin_amdgcn_mfma_f32_16x16x32_bf16(Alo, Bhi, acc3[p], 0, 0, 0);
            acc3[p] = __builtin_amdgcn_mfma_f32_16x16x32_bf16(Ahi, Blo, acc3[p], 0, 0, 0);
        }
    }
    int dd = w * 16 + rit;
    if (dd < DDIM) {
        int b = r0 / (TT * NNODE), t = (r0 / NNODE) % TT, nn0 = r0 % NNODE;
        int trow0 = t * BN + b * NNODE + nn0;
        #pragma unroll
        for (int p = 0; p < 3; ++p) {
            float bias = bfold[p * DDIM + dd];
            #pragma unroll
            for (int j = 0; j < 4; ++j) {
                int row = kgrp * 4 + j;
                GI[(trow0 + row) * 336 + p * 112 + dd] = acc3[p][j] + bias;
            }
        }
    }
}

// ---------------------------------------------------------------------------
// L3: outer temporal GRU via split-bf16 MFMA (blocks [0,100))
//   + bf16 pack of BW/Wh (blocks [100,208)).
__global__ __launch_bounds__(448) void k_mid2(const float* __restrict__ GI,
    const bf16x8* __restrict__ WOH, const bf16x8* __restrict__ WOL,
    float* __restrict__ Hall,
    const float* __restrict__ BW, const float* __restrict__ g_whh,
    bf16x8* __restrict__ BWpk, bf16x8* __restrict__ WHpk) {
    __shared__ float h_lds[16 * 112];
    int tid = threadIdx.x;
    if (blockIdx.x >= 100) {                // pack BW (K=1024) and Wh (K=128)
        int i = (blockIdx.x - 100) * 448 + tid;
        if (i < 43008) {
            int l = i & 63, c = (i >> 6) % 21, kt = i / (21 * 64);
            int col = c * 16 + (l & 15);
            int gate = col / 112, o = col % 112;
            bf16x8 r;
            #pragma unroll
            for (int j = 0; j < 8; ++j) {
                int kk = kt * 32 + ((l >> 4) << 3) + j;
                float v = (kk < 1000 && o < DDIM) ? BW[kk * 300 + gate * DDIM + o] : 0.f;
                r[j] = bfc(v);
            }
            BWpk[i] = r;
        } else if (i < 48384) {
            int id = i - 43008;
            int l = id & 63, c = (id >> 6) % 21, kt2 = id / (21 * 64);
            int col = c * 16 + (l & 15);
            int gate = col / 112, o = col % 112;
            bf16x8 r;
            #pragma unroll
            for (int j = 0; j < 8; ++j) {
                int k = kt2 * 32 + ((l >> 4) << 3) + j;
                float v = (k < DDIM && o < DDIM) ? g_whh[(gate * DDIM + o) * DDIM + k] : 0.f;
                r[j] = bfc(v);
            }
            WHpk[id] = r;
        }
        return;
    }
    // temporal GRU: 16 nodes/block
    int bn0 = blockIdx.x * 16;
    for (int idx = tid; idx < 16 * 112; idx += 448) h_lds[idx] = 0.f;
    __syncthreads();
    int w = tid >> 6, l = tid & 63, rit = l & 15, kgrp = l >> 4;
    int dd = w * 16 + rit;
    for (int t = 0; t < TT; ++t) {
        float gir[4], giz[4], gin[4], hold[4];
        if (dd < DDIM) {
            #pragma unroll
            for (int j = 0; j < 4; ++j) {
                int node = kgrp * 4 + j;
                int trow = t * BN + bn0 + node;
                gir[j] = GI[trow * 336 + dd];
                giz[j] = GI[trow * 336 + 112 + dd];
                gin[j] = GI[trow * 336 + 224 + dd];
                hold[j] = h_lds[node * 112 + dd];
            }
        }
        f32x4 a0 = (f32x4){0.f, 0.f, 0.f, 0.f};
        f32x4 a1 = (f32x4){0.f, 0.f, 0.f, 0.f};
        f32x4 a2 = (f32x4){0.f, 0.f, 0.f, 0.f};
        if (t > 0) {
            for (int kt = 0; kt < 4; ++kt) {
                bf16x8 Ahi, Alo;
                #pragma unroll
                for (int j = 0; j < 8; ++j) {
                    int k = kt * 32 + kgrp * 8 + j;
                    float v = (k < DDIM) ? h_lds[rit * 112 + k] : 0.f;
                    short hi = bfc(v);
                    Ahi[j] = hi;
                    Alo[j] = bfc(v - bf2f(hi));
                }
                {
                    bf16x8 Bhi = WOH[(kt * 21 + w) * 64 + l];
                    bf16x8 Blo = WOL[(kt * 21 + w) * 64 + l];
                    a0 = __builtin_amdgcn_mfma_f32_16x16x32_bf16(Ahi, Bhi, a0, 0, 0, 0);
                    a0 = __builtin_amdgcn_mfma_f32_16x16x32_bf16(Alo, Bhi, a0, 0, 0, 0);
                    a0 = __builtin_amdgcn_mfma_f32_16x16x32_bf16(Ahi, Blo, a0, 0, 0, 0);
                }
                {
                    bf16x8 Bhi = WOH[(kt * 21 + w + 7) * 64 + l];
                    bf16x8 Blo = WOL[(kt * 21 + w + 7) * 64 + l];
                    a1 = __builtin_amdgcn_mfma_f32_16x16x32_bf16(Ahi, Bhi, a1, 0, 0, 0);
                    a1 = __builtin_amdgcn_mfma_f32_16x16x32_bf16(Alo, Bhi, a1, 0, 0, 0);
                    a1 = __builtin_amdgcn_mfma_f32_16x16x32_bf16(Ahi, Blo, a1, 0, 0, 0);
                }
                {
                    bf16x8 Bhi = WOH[(kt * 21 + w + 14) * 64 + l];
                    bf16x8 Blo = WOL[(kt * 21 + w + 14) * 64 + l];
                    a2 = __builtin_amdgcn_mfma_f32_16x16x32_bf16(Ahi, Bhi, a2, 0, 0, 0);
                    a2 = __builtin_amdgcn_mfma_f32_16x16x32_bf16(Alo, Bhi, a2, 0, 0, 0);
                    a2 = __builtin_amdgcn_mfma_f32_16x16x32_bf16(Ahi, Blo, a2, 0, 0, 0);
                }
            }
        }
        __syncthreads();
        if (dd < DDIM) {
            #pragma unroll
            for (int j = 0; j < 4; ++j) {
                int node = kgrp * 4 + j;
                int trow = t * BN + bn0 + node;
                float r = sigf(gir[j] + a0[j]);
                float z = sigf(giz[j] + a1[j]);
                float nn = tanhf(gin[j] + r * a2[j]);
                float hnew = (1.f - z) * nn + z * hold[j];
                h_lds[node * 112 + dd] = hnew;
                Hall[trow * DDIM + dd] = hnew;
            }
        }
        __syncthreads();
    }
}

// ---------------------------------------------------------------------------
// L4: fused gather + inner GRU, 16 rows/block (600 blocks, 32KB LDS).
// Gather: chunks of 4 edges — packed records loaded back-to-back, then all
// Hall float2 loads issued independently (ILP), then static-index accumulate.
__global__ __launch_bounds__(448) void k_fused16(
    const int* __restrict__ start, const int2* __restrict__ sortedE2,
    const bf16x8* __restrict__ BWpk, const bf16x8* __restrict__ WHpk,
    const float* __restrict__ bI, const float* __restrict__ bH,
    const float* __restrict__ Hall, const float* __restrict__ visv,
    const float* __restrict__ inv_nv, float* __restrict__ out,
    float* __restrict__ gout) {
    __shared__ unsigned lds[8192];           // 16 rows x 512 words
    int tid = threadIdx.x;
    int w = tid >> 6, l = tid & 63;
    int rit = l & 15, kgrp = l >> 4;
    int rbase = blockIdx.x * 16;

    // ---- gather phase: wave w handles rows w, w+7 (and w+14 for w<2) ----
    for (int r = w; r < 16; r += 7) {
        int trd = rbase + r;
        int s0 = start[trd], s1 = start[trd + 1];
        int rowbase = (trd / NNODE) * NNODE;
        float acc[16];
        #pragma unroll
        for (int j = 0; j < 16; ++j) acc[j] = 0.f;
        for (int e0 = s0; e0 < s1; e0 += 4) {
            float2 hA[4], hB[4];
            float me[4];
            int ge[4];
            #pragma unroll
            for (int e = 0; e < 4; ++e) {
                int idx = e0 + e;
                int2 rec = (idx < s1) ? sortedE2[idx] : make_int2(0, 0);
                int src = rec.x & 0xffff;
                int g = rec.x >> 16;
                ge[e] = g;
                me[e] = __int_as_float(rec.y);
                const float* hs = Hall + (size_t)(rowbase + src) * DDIM;
                int k0 = g * 100;
                int J0 = k0 >> 7, J1 = (k0 + 99) >> 7;
                int sA = 128 * J0 + 2 * l, sB = 128 * J1 + 2 * l;
                bool aA = (sA >= k0) && (sA < k0 + 100);
                bool aB = (J1 != J0) && (sB >= k0) && (sB < k0 + 100);
                hA[e] = aA ? *(const float2*)(hs + (sA - k0)) : make_float2(0.f, 0.f);
                hB[e] = aB ? *(const float2*)(hs + (sB - k0)) : make_float2(0.f, 0.f);
            }
            #pragma unroll
            for (int e = 0; e < 4; ++e) {
                float m = me[e];
                float ax = m * hA[e].x, ay = m * hA[e].y;
                float bx = m * hB[e].x, by = m * hB[e].y;
                switch (ge[e]) {             // static acc indices per case
                    case 0: acc[0] += ax; acc[1] += ay; break;
                    case 1: acc[0] += ax; acc[1] += ay; acc[2] += bx; acc[3] += by; break;
                    case 2: acc[2] += ax; acc[3] += ay; acc[4] += bx; acc[5] += by; break;
                    case 3: acc[4] += ax; acc[5] += ay; acc[6] += bx; acc[7] += by; break;
                    case 4: acc[6] += ax; acc[7] += ay; break;
                    case 5: acc[6] += ax; acc[7] += ay; acc[8] += bx; acc[9] += by; break;
                    case 6: acc[8] += ax; acc[9] += ay; acc[10] += bx; acc[11] += by; break;
                    case 7: acc[10] += ax; acc[11] += ay; acc[12] += bx; acc[13] += by; break;
                    case 8: acc[12] += ax; acc[13] += ay; acc[14] += bx; acc[15] += by; break;
                    case 9: acc[14] += ax; acc[15] += ay; break;
                }
            }
        }
        #pragma unroll
        for (int j = 0; j < 8; ++j) {        // word 64j+l = slots (128j+2l, +1)
            unsigned word = cvtpk(acc[2 * j], acc[2 * j + 1]);
            int g16 = 16 * j + (l >> 2);
            int wd = r * 512 + ((g16 * 4) ^ ((r & 7) << 2)) + (l & 3);
            lds[wd] = word;
        }
    }
    __syncthreads();

    f32x4 acc[3];
    acc[0] = acc[1] = acc[2] = (f32x4){0.f, 0.f, 0.f, 0.f};

    for (int kt = 0; kt < 32; ++kt) {        // gi = U @ BW (K=1024)
        bf16x8 fb0 = BWpk[(kt * 21 + w) * 64 + l];
        bf16x8 fb1 = BWpk[(kt * 21 + w + 7) * 64 + l];
        bf16x8 fb2 = BWpk[(kt * 21 + w + 14) * 64 + l];
        int wd = rit * 512 + (((kt * 16 + kgrp * 4)) ^ ((rit & 7) << 2));
        bf16x8 fa = *(bf16x8*)&lds[wd];
        acc[0] = __builtin_amdgcn_mfma_f32_16x16x32_bf16(fa, fb0, acc[0], 0, 0, 0);
        acc[1] = __builtin_amdgcn_mfma_f32_16x16x32_bf16(fa, fb1, acc[1], 0, 0, 0);
        acc[2] = __builtin_amdgcn_mfma_f32_16x16x32_bf16(fa, fb2, acc[2], 0, 0, 0);
    }
    __syncthreads();

    for (int i = tid; i < 256; i += 448) {   // restage Hall (bf16, K pad 128)
        int row = i >> 4, g16 = i & 15;
        int k0 = g16 * 8;
        const float* hs = Hall + (size_t)(rbase + row) * DDIM;
        float v[8];
        #pragma unroll
        for (int jj = 0; jj < 8; ++jj)
            v[jj] = (k0 + jj < DDIM) ? hs[k0 + jj] : 0.f;
        int4 wv;
        wv.x = (int)cvtpk(v[0], v[1]);
        wv.y = (int)cvtpk(v[2], v[3]);
        wv.z = (int)cvtpk(v[4], v[5]);
        wv.w = (int)cvtpk(v[6], v[7]);
        int wd = row * 64 + ((g16 * 4) ^ ((row & 7) << 2));
        *(int4*)&lds[wd] = wv;
    }
    __syncthreads();

    f32x4 hacc = (f32x4){0.f, 0.f, 0.f, 0.f};
    for (int kt2 = 0; kt2 < 4; ++kt2) {
        bf16x8 fb0 = WHpk[(kt2 * 21 + w) * 64 + l];
        bf16x8 fb1 = WHpk[(kt2 * 21 + w + 7) * 64 + l];
        bf16x8 fb2 = WHpk[(kt2 * 21 + w + 14) * 64 + l];
        int wd = rit * 64 + (((kt2 * 16 + kgrp * 4)) ^ ((rit & 7) << 2));
        bf16x8 fh = *(bf16x8*)&lds[wd];
        acc[0] = __builtin_amdgcn_mfma_f32_16x16x32_bf16(fh, fb0, acc[0], 0, 0, 0);
        acc[1] = __builtin_amdgcn_mfma_f32_16x16x32_bf16(fh, fb1, acc[1], 0, 0, 0);
        hacc   = __builtin_amdgcn_mfma_f32_16x16x32_bf16(fh, fb2, hacc, 0, 0, 0);
    }

    int col = w * 16 + rit;
    if (col < DDIM) {
        float bIr = bI[col], bIz = bI[112 + col], bIn = bI[224 + col];
        float bHr = bH[col], bHz = bH[112 + col], bHn = bH[224 + col];
        int t = rbase / BN, r2 = rbase % BN, b = r2 / NNODE, n0 = r2 % NNODE;
        int bt = b * TT + t;
        int trow0 = rbase + kgrp * 4;
        int brow0 = bt * NNODE + n0 + kgrp * 4;
        float gs = 0.f;
        #pragma unroll
        for (int j = 0; j < 4; ++j) {
            float r = sigf(acc[0][j] + bIr + bHr);
            float z = sigf(acc[1][j] + bIz + bHz);
            float ghn = hacc[j] + bHn;
            float nn = tanhf(acc[2][j] + bIn + r * ghn);
            float hold = Hall[(trow0 + j) * DDIM + col];
            float feat = (1.f - z) * nn + z * hold;
            int brow = brow0 + j;
            float v = visv[brow];
            float outv = feat * v;
            out[brow * DDIM + col] = outv;
            gs += outv * v;                  // reference applies vis twice in mean
        }
        gs += __shfl_xor(gs, 16, 64);
        gs += __shfl_xor(gs, 32, 64);
        if (kgrp == 0)
            atomicAdd(&gout[bt * DDIM + col], gs * inv_nv[bt]);
    }
}

// ---------------------------------------------------------------------------
extern "C" void kernel_launch(void* const* d_in, const int* in_sizes, int n_in,
                              void* d_out, int out_size, void* d_ws, size_t ws_size,
                              hipStream_t stream) {
    const int*   class_names = (const int*)d_in[0];
    const float* states      = (const float*)d_in[1];
    const int*   edges       = (const int*)d_in[2];
    const int*   edge_types  = (const int*)d_in[3];
    const float* visibility  = (const float*)d_in[4];
    const float* mask_edges  = (const float*)d_in[5];
    const float* obj_emb     = (const float*)d_in[6];
    const float* state_W     = (const float*)d_in[7];
    const float* state_b     = (const float*)d_in[8];
    const float* c1_W        = (const float*)d_in[9];
    const float* c1_b        = (const float*)d_in[10];
    const float* c2_W        = (const float*)d_in[11];
    const float* c2_b        = (const float*)d_in[12];
    const float* edge_embed  = (const float*)d_in[13];
    const float* g_wih       = (const float*)d_in[14];
    const float* g_whh       = (const float*)d_in[15];
    const float* g_bih       = (const float*)d_in[16];
    const float* g_bhh       = (const float*)d_in[17];
    const float* o_wih       = (const float*)d_in[18];
    const float* o_whh       = (const float*)d_in[19];

    float* out = (float*)d_out;
    float* gout = out + (size_t)NROW * DDIM;
    float* ws  = (float*)d_ws;
    float*  pre1  = ws + OFF_PRE1;
    float*  QT    = ws + OFF_QT;
    float*  bQ    = ws + OFF_BQ;
    float*  bfold = ws + OFF_BF;
    float*  WiT   = ws + OFF_WIT;
    float*  bI    = ws + OFF_BI;
    float*  bH    = ws + OFF_BH;
    ushort* WFH   = (ushort*)(ws + OFF_WFH);
    ushort* WFL   = (ushort*)(ws + OFF_WFL);
    ushort* WOH   = (ushort*)(ws + OFF_WOH);
    ushort* WOL   = (ushort*)(ws + OFF_WOL);
    float*  BWf   = ws + OFF_BWF;
    bf16x8* BWpk  = (bf16x8*)(ws + OFF_BWPK);
    bf16x8* WHpk  = (bf16x8*)(ws + OFF_WHPK);
    float*  Hall  = ws + OFF_HALL;
    int*    start = (int*)(ws + OFF_START);
    int2*   sortedE2 = (int2*)(ws + OFF_SE);
    float*  inv_nv= ws + OFF_INV;
    float*  GI    = ws + OFF_GI;

    // L1: prep + packs + inv_nv + zero(gout) + per-chunk packed bin-sort
    k_front<<<626, 256, 0, stream>>>(obj_emb, c1_W, c1_b, state_W, state_b,
                                     c2_W, c2_b, o_wih, o_whh, g_wih, g_bih, g_bhh,
                                     visibility, edges, edge_types, mask_edges,
                                     pre1, QT, bQ, bfold, WiT, bI, bH,
                                     WFH, WFL, WOH, WOL, inv_nv, gout,
                                     start, sortedE2);
    // L2: BW_f32 + GI (MFMA)
    k_mid<<<1270, 448, 0, stream>>>(edge_embed, WiT, BWf, class_names, states,
                                    pre1, QT, bQ, bfold,
                                    (const bf16x8*)WFH, (const bf16x8*)WFL, GI);
    // L3: outer GRU (MFMA) + bf16 pack
    k_mid2<<<208, 448, 0, stream>>>(GI, (const bf16x8*)WOH, (const bf16x8*)WOL,
                                    Hall, BWf, g_whh, BWpk, WHpk);
    // L4: fused gather + inner GRU + visibility mask + global mean
    k_fused16<<<NROW / 16, 448, 0, stream>>>(start, sortedE2, BWpk, WHpk, bI, bH,
                                             Hall, visibility, inv_nv, out, gout);
}

// Round 7
// 104.650 us; speedup vs baseline: 1.2236x; 1.1282x over previous
//
#include <hip/hip_runtime.h>

#define BSZ   4
#define TT    6
#define NNODE 400
#define EED   3000
#define DDIM  100
#define NSDIM 30
#define NETYP 10
#define BN    (BSZ*NNODE)                    // 1600
#define NROW  (BSZ*TT*NNODE)                 // 9600
#define NEDGE (BSZ*TT*EED)                   // 72000
#define KPAD  1024

// workspace float offsets
#define OFF_PRE1 0               // 30000
#define OFF_QT   30000           // 3000
#define OFF_BQ   33000           // 100 -> 33104
#define OFF_BF   33104           // 300 -> 33408
#define OFF_WIT  33408           // 30000 -> 63408
#define OFF_BI   63408           // 336
#define OFF_BH   63744           // 336 -> 64080
#define OFF_WFH  64080           // 21504 -> 85584
#define OFF_WFL  85584           // 21504 -> 107088
#define OFF_WOH  107088          // 21504 -> 128592
#define OFF_WOL  128592          // 21504 -> 150096
#define OFF_BWF  150096          // 300000 -> 450096
#define OFF_BWPK 450096          // 172032 -> 622128
#define OFF_WHPK 622128          // 21504 -> 643632
#define OFF_HALL 643632          // 960000 -> 1603632
#define OFF_START 1603632        // 9601 -> pad 1613236
#define OFF_SE   1613236         // 72000 int2 = 144000 -> 1757236
#define OFF_INV  1757248         // 24 -> pad 1757280
#define OFF_GI   1757280         // 9600*336 = 3225600 -> 4982880
#define OFF_UB   4982880         // 9600*1024 ushort = 2457600 floats -> 7440480

typedef __attribute__((ext_vector_type(8))) short bf16x8;
typedef __attribute__((ext_vector_type(4))) float f32x4;

__device__ __forceinline__ float sigf(float v) { return 1.0f / (1.0f + expf(-v)); }

__device__ __forceinline__ short bfc(float f) {   // f32 -> bf16 bits, RNE
    union { float f; unsigned u; } v; v.f = f;
    unsigned r = v.u + 0x7fffu + ((v.u >> 16) & 1u);
    return (short)(r >> 16);
}

__device__ __forceinline__ float bf2f(short h) {
    union { unsigned u; float f; } x; x.u = ((unsigned)(unsigned short)h) << 16;
    return x.f;
}

__device__ __forceinline__ unsigned cvtpk(float lo, float hi) {
    unsigned r;
    asm("v_cvt_pk_bf16_f32 %0, %1, %2" : "=v"(r) : "v"(lo), "v"(hi));
    return r;
}

// ---------------------------------------------------------------------------
// L1: blocks [0,24): per-(t,b) in-block counting sort of edges by dst row;
//     sorted records packed {src|g<<16, m}.
//     blocks [24,626): weight precomputes + inv_nv + gout zero.
__global__ __launch_bounds__(256) void k_front(
    const float* __restrict__ obj_emb, const float* __restrict__ c1_W,
    const float* __restrict__ c1_b, const float* __restrict__ state_W,
    const float* __restrict__ state_b, const float* __restrict__ c2_W,
    const float* __restrict__ c2_b, const float* __restrict__ o_wih,
    const float* __restrict__ o_whh, const float* __restrict__ g_wih,
    const float* __restrict__ g_bih, const float* __restrict__ g_bhh,
    const float* __restrict__ vis, const int* __restrict__ edges,
    const int* __restrict__ etype, const float* __restrict__ emask,
    float* __restrict__ pre1, float* __restrict__ QT, float* __restrict__ bQ,
    float* __restrict__ bfold, float* __restrict__ WiT,
    float* __restrict__ bI, float* __restrict__ bH,
    ushort* __restrict__ WFH, ushort* __restrict__ WFL,
    ushort* __restrict__ WOH, ushort* __restrict__ WOL,
    float* __restrict__ inv_nv, float* __restrict__ gout,
    int* __restrict__ start, int2* __restrict__ sortedE2) {
    int tid = threadIdx.x;
    if (blockIdx.x < 24) {                  // bin-sort chunk c = t*4+b
        __shared__ int hcnt[400];
        __shared__ int hstart[400];
        int c = blockIdx.x;
        int t = c >> 2, b = c & 3;
        int febase = (b * TT + t) * EED;
        for (int i = tid; i < 400; i += 256) hcnt[i] = 0;
        __syncthreads();
        for (int i = tid; i < EED; i += 256)
            atomicAdd(&hcnt[edges[(febase + i) * 2 + 1]], 1);
        __syncthreads();
        if (tid < 64) {                     // exclusive prefix scan of 400 bins
            int lane = tid, carry = 0;
            for (int ch = 0; ch < 7; ++ch) {
                int idx = ch * 64 + lane;
                int orig = (idx < 400) ? hcnt[idx] : 0;
                int v = orig;
                #pragma unroll
                for (int off = 1; off < 64; off <<= 1) {
                    int u = __shfl_up(v, off, 64);
                    if (lane >= off) v += u;
                }
                if (idx < 400) hstart[idx] = carry + (v - orig);
                carry += __shfl(v, 63, 64);
            }
        }
        __syncthreads();
        for (int i = tid; i < 400; i += 256) {
            start[c * 400 + i] = c * EED + hstart[i];
            hcnt[i] = hstart[i];            // reuse as cursor
        }
        if (c == 23 && tid == 0) start[NROW] = NEDGE;
        __syncthreads();
        for (int i = tid; i < EED; i += 256) {
            int fe = febase + i;
            int2 ed = *(const int2*)(edges + fe * 2);   // (src,dst)
            int pos = atomicAdd(&hcnt[ed.y], 1);
            int g = etype[fe];
            float m = emask[fe];
            sortedE2[c * EED + pos] = make_int2(ed.x | (g << 16), __float_as_int(m));
        }
        return;
    }
    int i = (blockIdx.x - 24) * 256 + tid;
    if (i < 30000) {                        // pre1[cls][d1]
        int cls = i / DDIM, d1 = i % DDIM;
        float acc = 0.f;
        for (int k = 0; k < DDIM; ++k)
            acc += obj_emb[cls * DDIM + k] * c1_W[d1 * 2 * DDIM + k];
        pre1[i] = acc;
    } else if (i < 33000) {                 // QT[s][d1]
        int j = i - 30000, s = j / DDIM, d1 = j % DDIM;
        float acc = 0.f;
        for (int d = 0; d < DDIM; ++d)
            acc += c1_W[d1 * 2 * DDIM + DDIM + d] * state_W[d * NSDIM + s];
        QT[j] = acc;
    } else if (i < 33100) {                 // bQ[d1]
        int d1 = i - 33000;
        float acc = c1_b[d1];
        for (int d = 0; d < DDIM; ++d)
            acc += state_b[d] * c1_W[d1 * 2 * DDIM + DDIM + d];
        bQ[d1] = acc;
    } else if (i < 33400) {                 // bfold[o]
        int o = i - 33100;
        float acc = 0.f;
        for (int d = 0; d < DDIM; ++d)
            acc += o_wih[o * DDIM + d] * c2_b[d];
        bfold[o] = acc;
    } else if (i < 76408) {                 // WFpk hi/lo
        int e = i - 33400;
        int j = e & 7, frag = e >> 3;
        int l = frag & 63, ct = (frag >> 6) % 21, kt = frag / (21 * 64);
        int col = ct * 16 + (l & 15);
        int gate = col / 112, dd = col % 112;
        int k = kt * 32 + ((l >> 4) << 3) + j;
        float v = 0.f;
        if (k < DDIM && dd < DDIM) {
            int o = gate * DDIM + dd;
            for (int d = 0; d < DDIM; ++d)
                v += o_wih[o * DDIM + d] * c2_W[d * DDIM + k];
        }
        short hi = bfc(v);
        WFH[frag * 8 + j] = (ushort)hi;
        WFL[frag * 8 + j] = (ushort)bfc(v - bf2f(hi));
    } else if (i < 119416) {                // WOpk hi/lo = o_whh^T
        int e = i - 76408;
        int j = e & 7, frag = e >> 3;
        int l = frag & 63, ct = (frag >> 6) % 21, kt = frag / (21 * 64);
        int col = ct * 16 + (l & 15);
        int gate = col / 112, dd = col % 112;
        int k = kt * 32 + ((l >> 4) << 3) + j;
        float v = 0.f;
        if (k < DDIM && dd < DDIM)
            v = o_whh[(gate * DDIM + dd) * DDIM + k];
        short hi = bfc(v);
        WOH[frag * 8 + j] = (ushort)hi;
        WOL[frag * 8 + j] = (ushort)bfc(v - bf2f(hi));
    } else if (i < 149416) {                // WiT[j][go] = g_wih^T
        int j = i - 119416, k = j / 300, o = j % 300;
        WiT[j] = g_wih[o * DDIM + k];
    } else if (i < 149752) {                // bI[col]
        int col = i - 149416, gate = col / 112, o = col % 112;
        bI[col] = (o < DDIM) ? g_bih[gate * DDIM + o] : 0.f;
    } else if (i < 150088) {                // bH[col]
        int col = i - 149752, gate = col / 112, o = col % 112;
        bH[col] = (o < DDIM) ? g_bhh[gate * DDIM + o] : 0.f;
    } else if (i >= 150144 && i < 151680) { // inv_nv[bt]
        int g = (i - 150144) >> 6;
        int lane = i & 63;
        float s = 0.f;
        for (int n = lane; n < NNODE; n += 64)
            s += vis[g * NNODE + n];
        #pragma unroll
        for (int off = 32; off > 0; off >>= 1)
            s += __shfl_down(s, off, 64);
        if (lane == 0) inv_nv[g] = 1.f / (s + 1e-9f);
    } else if (i >= 151680 && i < 154080) { // zero gout
        gout[i - 151680] = 0.f;
    }
}

// ---------------------------------------------------------------------------
// L2: BW_f32 (blocks [0,670)) + GI via split-bf16 MFMA (blocks [670,1270)).
__global__ __launch_bounds__(448) void k_mid(
    const float* __restrict__ edge_embed, const float* __restrict__ WiT,
    float* __restrict__ BW,
    const int* __restrict__ cls, const float* __restrict__ states,
    const float* __restrict__ pre1, const float* __restrict__ QT,
    const float* __restrict__ bQ, const float* __restrict__ bfold,
    const bf16x8* __restrict__ WFH, const bf16x8* __restrict__ WFL,
    float* __restrict__ GI) {
    __shared__ float st_lds[16 * NSDIM];
    __shared__ float hid_lds[16 * 112];
    __shared__ int cls_lds[16];
    int tid = threadIdx.x;
    if (blockIdx.x < 670) {                 // BW[kk][go]
        int i = blockIdx.x * 448 + tid;
        if (i < 1000 * 300) {
            int kk = i / 300, go = i % 300;
            int g = kk / DDIM, k = kk % DDIM;
            const float* es = edge_embed + g * DDIM * DDIM + k;
            float acc = 0.f;
            for (int j = 0; j < DDIM; ++j)
                acc += es[j * DDIM] * WiT[j * 300 + go];
            BW[i] = acc;
        }
        return;
    }
    // GI: hid = relu(pre1+states@Q^T+bQ); GI = hid @ WF + bfold (MFMA)
    int r0 = (blockIdx.x - 670) * 16;
    for (int idx = tid; idx < 16 * NSDIM; idx += 448) st_lds[idx] = states[r0 * NSDIM + idx];
    if (tid < 16) cls_lds[tid] = cls[r0 + tid];
    __syncthreads();
    #pragma unroll
    for (int u = 0; u < 4; ++u) {
        int it = tid + u * 448;
        if (it < 1600) {
            int n = it / 100, d = it % 100;
            float acc = bQ[d] + pre1[cls_lds[n] * DDIM + d];
            for (int s = 0; s < NSDIM; ++s)
                acc += QT[s * DDIM + d] * st_lds[n * NSDIM + s];
            hid_lds[n * 112 + d] = fmaxf(acc, 0.f);
        }
    }
    __syncthreads();
    int w = tid >> 6, l = tid & 63, rit = l & 15, kgrp = l >> 4;
    f32x4 acc3[3];
    acc3[0] = acc3[1] = acc3[2] = (f32x4){0.f, 0.f, 0.f, 0.f};
    for (int kt = 0; kt < 4; ++kt) {
        bf16x8 Ahi, Alo;
        #pragma unroll
        for (int j = 0; j < 8; ++j) {
            int k = kt * 32 + kgrp * 8 + j;
            float v = (k < DDIM) ? hid_lds[rit * 112 + k] : 0.f;
            short hi = bfc(v);
            Ahi[j] = hi;
            Alo[j] = bfc(v - bf2f(hi));
        }
        #pragma unroll
        for (int p = 0; p < 3; ++p) {
            int ct = w + p * 7;
            bf16x8 Bhi = WFH[(kt * 21 + ct) * 64 + l];
            bf16x8 Blo = WFL[(kt * 21 + ct) * 64 + l];
            acc3[p] = __builtin_amdgcn_mfma_f32_16x16x32_bf16(Ahi, Bhi, acc3[p], 0, 0, 0);
            acc3[p] = __builtin_amdgcn_mfma_f32_16x16x32_bf16(Alo, Bhi, acc3[p], 0, 0, 0);
            acc3[p] = __builtin_amdgcn_mfma_f32_16x16x32_bf16(Ahi, Blo, acc3[p], 0, 0, 0);
        }
    }
    int dd = w * 16 + rit;
    if (dd < DDIM) {
        int b = r0 / (TT * NNODE), t = (r0 / NNODE) % TT, nn0 = r0 % NNODE;
        int trow0 = t * BN + b * NNODE + nn0;
        #pragma unroll
        for (int p = 0; p < 3; ++p) {
            float bias = bfold[p * DDIM + dd];
            #pragma unroll
            for (int j = 0; j < 4; ++j) {
                int row = kgrp * 4 + j;
                GI[(trow0 + row) * 336 + p * 112 + dd] = acc3[p][j] + bias;
            }
        }
    }
}

// ---------------------------------------------------------------------------
// L3: outer temporal GRU via split-bf16 MFMA (blocks [0,100))
//   + bf16 pack of BW/Wh (blocks [100,208)).
__global__ __launch_bounds__(448) void k_mid2(const float* __restrict__ GI,
    const bf16x8* __restrict__ WOH, const bf16x8* __restrict__ WOL,
    float* __restrict__ Hall,
    const float* __restrict__ BW, const float* __restrict__ g_whh,
    bf16x8* __restrict__ BWpk, bf16x8* __restrict__ WHpk) {
    __shared__ float h_lds[16 * 112];
    int tid = threadIdx.x;
    if (blockIdx.x >= 100) {                // pack BW (K=1024) and Wh (K=128)
        int i = (blockIdx.x - 100) * 448 + tid;
        if (i < 43008) {
            int l = i & 63, c = (i >> 6) % 21, kt = i / (21 * 64);
            int col = c * 16 + (l & 15);
            int gate = col / 112, o = col % 112;
            bf16x8 r;
            #pragma unroll
            for (int j = 0; j < 8; ++j) {
                int kk = kt * 32 + ((l >> 4) << 3) + j;
                float v = (kk < 1000 && o < DDIM) ? BW[kk * 300 + gate * DDIM + o] : 0.f;
                r[j] = bfc(v);
            }
            BWpk[i] = r;
        } else if (i < 48384) {
            int id = i - 43008;
            int l = id & 63, c = (id >> 6) % 21, kt2 = id / (21 * 64);
            int col = c * 16 + (l & 15);
            int gate = col / 112, o = col % 112;
            bf16x8 r;
            #pragma unroll
            for (int j = 0; j < 8; ++j) {
                int k = kt2 * 32 + ((l >> 4) << 3) + j;
                float v = (k < DDIM && o < DDIM) ? g_whh[(gate * DDIM + o) * DDIM + k] : 0.f;
                r[j] = bfc(v);
            }
            WHpk[id] = r;
        }
        return;
    }
    // temporal GRU: 16 nodes/block
    int bn0 = blockIdx.x * 16;
    for (int idx = tid; idx < 16 * 112; idx += 448) h_lds[idx] = 0.f;
    __syncthreads();
    int w = tid >> 6, l = tid & 63, rit = l & 15, kgrp = l >> 4;
    int dd = w * 16 + rit;
    for (int t = 0; t < TT; ++t) {
        float gir[4], giz[4], gin[4], hold[4];
        if (dd < DDIM) {
            #pragma unroll
            for (int j = 0; j < 4; ++j) {
                int node = kgrp * 4 + j;
                int trow = t * BN + bn0 + node;
                gir[j] = GI[trow * 336 + dd];
                giz[j] = GI[trow * 336 + 112 + dd];
                gin[j] = GI[trow * 336 + 224 + dd];
                hold[j] = h_lds[node * 112 + dd];
            }
        }
        f32x4 a0 = (f32x4){0.f, 0.f, 0.f, 0.f};
        f32x4 a1 = (f32x4){0.f, 0.f, 0.f, 0.f};
        f32x4 a2 = (f32x4){0.f, 0.f, 0.f, 0.f};
        if (t > 0) {
            for (int kt = 0; kt < 4; ++kt) {
                bf16x8 Ahi, Alo;
                #pragma unroll
                for (int j = 0; j < 8; ++j) {
                    int k = kt * 32 + kgrp * 8 + j;
                    float v = (k < DDIM) ? h_lds[rit * 112 + k] : 0.f;
                    short hi = bfc(v);
                    Ahi[j] = hi;
                    Alo[j] = bfc(v - bf2f(hi));
                }
                {
                    bf16x8 Bhi = WOH[(kt * 21 + w) * 64 + l];
                    bf16x8 Blo = WOL[(kt * 21 + w) * 64 + l];
                    a0 = __builtin_amdgcn_mfma_f32_16x16x32_bf16(Ahi, Bhi, a0, 0, 0, 0);
                    a0 = __builtin_amdgcn_mfma_f32_16x16x32_bf16(Alo, Bhi, a0, 0, 0, 0);
                    a0 = __builtin_amdgcn_mfma_f32_16x16x32_bf16(Ahi, Blo, a0, 0, 0, 0);
                }
                {
                    bf16x8 Bhi = WOH[(kt * 21 + w + 7) * 64 + l];
                    bf16x8 Blo = WOL[(kt * 21 + w + 7) * 64 + l];
                    a1 = __builtin_amdgcn_mfma_f32_16x16x32_bf16(Ahi, Bhi, a1, 0, 0, 0);
                    a1 = __builtin_amdgcn_mfma_f32_16x16x32_bf16(Alo, Bhi, a1, 0, 0, 0);
                    a1 = __builtin_amdgcn_mfma_f32_16x16x32_bf16(Ahi, Blo, a1, 0, 0, 0);
                }
                {
                    bf16x8 Bhi = WOH[(kt * 21 + w + 14) * 64 + l];
                    bf16x8 Blo = WOL[(kt * 21 + w + 14) * 64 + l];
                    a2 = __builtin_amdgcn_mfma_f32_16x16x32_bf16(Ahi, Bhi, a2, 0, 0, 0);
                    a2 = __builtin_amdgcn_mfma_f32_16x16x32_bf16(Alo, Bhi, a2, 0, 0, 0);
                    a2 = __builtin_amdgcn_mfma_f32_16x16x32_bf16(Ahi, Blo, a2, 0, 0, 0);
                }
            }
        }
        __syncthreads();
        if (dd < DDIM) {
            #pragma unroll
            for (int j = 0; j < 4; ++j) {
                int node = kgrp * 4 + j;
                int trow = t * BN + bn0 + node;
                float r = sigf(gir[j] + a0[j]);
                float z = sigf(giz[j] + a1[j]);
                float nn = tanhf(gin[j] + r * a2[j]);
                float hnew = (1.f - z) * nn + z * hold[j];
                h_lds[node * 112 + dd] = hnew;
                Hall[trow * DDIM + dd] = hnew;
            }
        }
        __syncthreads();
    }
}

// ---------------------------------------------------------------------------
// L4: gather, ONE WAVE PER ROW (9600 waves, max TLP). Chunks of 4 packed
// records (2-level load chain, ILP across the 4). Writes bf16 U row.
__global__ __launch_bounds__(256) void k_gather(
    const int* __restrict__ start, const int2* __restrict__ sortedE2,
    const float* __restrict__ Hall, unsigned* __restrict__ Ub2) {
    int gid = blockIdx.x * 256 + threadIdx.x;
    int trd = gid >> 6, l = gid & 63;
    int s0 = start[trd], s1 = start[trd + 1];
    int rowbase = (trd / NNODE) * NNODE;
    float acc[16];
    #pragma unroll
    for (int j = 0; j < 16; ++j) acc[j] = 0.f;
    for (int e0 = s0; e0 < s1; e0 += 4) {
        float2 hA[4], hB[4];
        float me[4];
        int ge[4];
        #pragma unroll
        for (int e = 0; e < 4; ++e) {
            int idx = e0 + e;
            int2 rec = (idx < s1) ? sortedE2[idx] : make_int2(0, 0);
            int src = rec.x & 0xffff;
            int g = rec.x >> 16;
            ge[e] = g;
            me[e] = __int_as_float(rec.y);
            const float* hs = Hall + (size_t)(rowbase + src) * DDIM;
            int k0 = g * 100;
            int J0 = k0 >> 7, J1 = (k0 + 99) >> 7;
            int sA = 128 * J0 + 2 * l, sB = 128 * J1 + 2 * l;
            bool aA = (sA >= k0) && (sA < k0 + 100);
            bool aB = (J1 != J0) && (sB >= k0) && (sB < k0 + 100);
            hA[e] = aA ? *(const float2*)(hs + (sA - k0)) : make_float2(0.f, 0.f);
            hB[e] = aB ? *(const float2*)(hs + (sB - k0)) : make_float2(0.f, 0.f);
        }
        #pragma unroll
        for (int e = 0; e < 4; ++e) {
            float m = me[e];
            float ax = m * hA[e].x, ay = m * hA[e].y;
            float bx = m * hB[e].x, by = m * hB[e].y;
            switch (ge[e]) {                 // static acc indices per case
                case 0: acc[0] += ax; acc[1] += ay; break;
                case 1: acc[0] += ax; acc[1] += ay; acc[2] += bx; acc[3] += by; break;
                case 2: acc[2] += ax; acc[3] += ay; acc[4] += bx; acc[5] += by; break;
                case 3: acc[4] += ax; acc[5] += ay; acc[6] += bx; acc[7] += by; break;
                case 4: acc[6] += ax; acc[7] += ay; break;
                case 5: acc[6] += ax; acc[7] += ay; acc[8] += bx; acc[9] += by; break;
                case 6: acc[8] += ax; acc[9] += ay; acc[10] += bx; acc[11] += by; break;
                case 7: acc[10] += ax; acc[11] += ay; acc[12] += bx; acc[13] += by; break;
                case 8: acc[12] += ax; acc[13] += ay; acc[14] += bx; acc[15] += by; break;
                case 9: acc[14] += ax; acc[15] += ay; break;
            }
        }
    }
    // linear bf16 row: slot 128j+2l,+1 -> ushort2 word at row*512 + 64j + l
    unsigned* urow = Ub2 + (size_t)trd * 512;
    #pragma unroll
    for (int j = 0; j < 8; ++j)
        urow[64 * j + l] = cvtpk(acc[2 * j], acc[2 * j + 1]);
}

// ---------------------------------------------------------------------------
// L5: fused inner GRU, 32 rows/block (300 blocks). U (bf16) staged from HBM.
__global__ __launch_bounds__(448) void k_fused32(const ushort* __restrict__ Ub,
    const bf16x8* __restrict__ BWpk, const bf16x8* __restrict__ WHpk,
    const float* __restrict__ bI, const float* __restrict__ bH,
    const float* __restrict__ Hall, const float* __restrict__ visv,
    const float* __restrict__ inv_nv, float* __restrict__ out,
    float* __restrict__ gout) {
    __shared__ unsigned lds[16384];          // 32 rows x 512 words
    int tid = threadIdx.x;
    int w = tid >> 6, l = tid & 63;
    int rit = l & 15, kgrp = l >> 4;
    int rbase = blockIdx.x * 32;

    for (int i = tid; i < 4096; i += 448) {  // stage U (bf16), XOR-swizzled
        int row = i >> 7, g16 = i & 127;
        int4 wv = *(const int4*)(Ub + (size_t)(rbase + row) * KPAD + g16 * 8);
        int wd = row * 512 + ((g16 * 4) ^ ((row & 7) << 2));
        *(int4*)&lds[wd] = wv;
    }
    __syncthreads();

    f32x4 acc[2][3];
    #pragma unroll
    for (int mt = 0; mt < 2; ++mt)
        #pragma unroll
        for (int q = 0; q < 3; ++q) acc[mt][q] = (f32x4){0.f, 0.f, 0.f, 0.f};

    for (int kt = 0; kt < 32; ++kt) {        // gi = U @ BW (K=1024)
        bf16x8 fb0 = BWpk[(kt * 21 + w) * 64 + l];
        bf16x8 fb1 = BWpk[(kt * 21 + w + 7) * 64 + l];
        bf16x8 fb2 = BWpk[(kt * 21 + w + 14) * 64 + l];
        #pragma unroll
        for (int mt = 0; mt < 2; ++mt) {
            int row = mt * 16 + rit;
            int wd = row * 512 + (((kt * 16 + kgrp * 4)) ^ ((row & 7) << 2));
            bf16x8 fa = *(bf16x8*)&lds[wd];
            acc[mt][0] = __builtin_amdgcn_mfma_f32_16x16x32_bf16(fa, fb0, acc[mt][0], 0, 0, 0);
            acc[mt][1] = __builtin_amdgcn_mfma_f32_16x16x32_bf16(fa, fb1, acc[mt][1], 0, 0, 0);
            acc[mt][2] = __builtin_amdgcn_mfma_f32_16x16x32_bf16(fa, fb2, acc[mt][2], 0, 0, 0);
        }
    }
    __syncthreads();

    for (int i = tid; i < 512; i += 448) {   // restage Hall (bf16, K pad 128)
        int row = i >> 4, g16 = i & 15;
        int k0 = g16 * 8;
        const float* hs = Hall + (size_t)(rbase + row) * DDIM;
        float v[8];
        #pragma unroll
        for (int jj = 0; jj < 8; ++jj)
            v[jj] = (k0 + jj < DDIM) ? hs[k0 + jj] : 0.f;
        int4 wv;
        wv.x = (int)cvtpk(v[0], v[1]);
        wv.y = (int)cvtpk(v[2], v[3]);
        wv.z = (int)cvtpk(v[4], v[5]);
        wv.w = (int)cvtpk(v[6], v[7]);
        int wd = row * 64 + ((g16 * 4) ^ ((row & 7) << 2));
        *(int4*)&lds[wd] = wv;
    }
    __syncthreads();

    f32x4 hacc[2];
    hacc[0] = (f32x4){0.f, 0.f, 0.f, 0.f};
    hacc[1] = (f32x4){0.f, 0.f, 0.f, 0.f};
    for (int kt2 = 0; kt2 < 4; ++kt2) {
        bf16x8 fb0 = WHpk[(kt2 * 21 + w) * 64 + l];
        bf16x8 fb1 = WHpk[(kt2 * 21 + w + 7) * 64 + l];
        bf16x8 fb2 = WHpk[(kt2 * 21 + w + 14) * 64 + l];
        #pragma unroll
        for (int mt = 0; mt < 2; ++mt) {
            int row = mt * 16 + rit;
            int wd = row * 64 + (((kt2 * 16 + kgrp * 4)) ^ ((row & 7) << 2));
            bf16x8 fh = *(bf16x8*)&lds[wd];
            acc[mt][0] = __builtin_amdgcn_mfma_f32_16x16x32_bf16(fh, fb0, acc[mt][0], 0, 0, 0);
            acc[mt][1] = __builtin_amdgcn_mfma_f32_16x16x32_bf16(fh, fb1, acc[mt][1], 0, 0, 0);
            hacc[mt]  = __builtin_amdgcn_mfma_f32_16x16x32_bf16(fh, fb2, hacc[mt], 0, 0, 0);
        }
    }

    int col = w * 16 + rit;
    if (col < DDIM) {
        float bIr = bI[col], bIz = bI[112 + col], bIn = bI[224 + col];
        float bHr = bH[col], bHz = bH[112 + col], bHn = bH[224 + col];
        int t = rbase / BN;
        #pragma unroll
        for (int mt = 0; mt < 2; ++mt) {
            int r2 = (rbase + mt * 16) % BN;
            int b = r2 / NNODE, n0 = r2 % NNODE;
            int bt = b * TT + t;
            int trow0 = rbase + mt * 16 + kgrp * 4;
            int brow0 = bt * NNODE + n0 + kgrp * 4;
            float gs = 0.f;
            #pragma unroll
            for (int j = 0; j < 4; ++j) {
                float r = sigf(acc[mt][0][j] + bIr + bHr);
                float z = sigf(acc[mt][1][j] + bIz + bHz);
                float ghn = hacc[mt][j] + bHn;
                float nn = tanhf(acc[mt][2][j] + bIn + r * ghn);
                float hold = Hall[(trow0 + j) * DDIM + col];
                float feat = (1.f - z) * nn + z * hold;
                int brow = brow0 + j;
                float v = visv[brow];
                float outv = feat * v;
                out[brow * DDIM + col] = outv;
                gs += outv * v;              // reference applies vis twice in mean
            }
            gs += __shfl_xor(gs, 16, 64);
            gs += __shfl_xor(gs, 32, 64);
            if (kgrp == 0)
                atomicAdd(&gout[bt * DDIM + col], gs * inv_nv[bt]);
        }
    }
}

// ---------------------------------------------------------------------------
extern "C" void kernel_launch(void* const* d_in, const int* in_sizes, int n_in,
                              void* d_out, int out_size, void* d_ws, size_t ws_size,
                              hipStream_t stream) {
    const int*   class_names = (const int*)d_in[0];
    const float* states      = (const float*)d_in[1];
    const int*   edges       = (const int*)d_in[2];
    const int*   edge_types  = (const int*)d_in[3];
    const float* visibility  = (const float*)d_in[4];
    const float* mask_edges  = (const float*)d_in[5];
    const float* obj_emb     = (const float*)d_in[6];
    const float* state_W     = (const float*)d_in[7];
    const float* state_b     = (const float*)d_in[8];
    const float* c1_W        = (const float*)d_in[9];
    const float* c1_b        = (const float*)d_in[10];
    const float* c2_W        = (const float*)d_in[11];
    const float* c2_b        = (const float*)d_in[12];
    const float* edge_embed  = (const float*)d_in[13];
    const float* g_wih       = (const float*)d_in[14];
    const float* g_whh       = (const float*)d_in[15];
    const float* g_bih       = (const float*)d_in[16];
    const float* g_bhh       = (const float*)d_in[17];
    const float* o_wih       = (const float*)d_in[18];
    const float* o_whh       = (const float*)d_in[19];

    float* out = (float*)d_out;
    float* gout = out + (size_t)NROW * DDIM;
    float* ws  = (float*)d_ws;
    float*  pre1  = ws + OFF_PRE1;
    float*  QT    = ws + OFF_QT;
    float*  bQ    = ws + OFF_BQ;
    float*  bfold = ws + OFF_BF;
    float*  WiT   = ws + OFF_WIT;
    float*  bI    = ws + OFF_BI;
    float*  bH    = ws + OFF_BH;
    ushort* WFH   = (ushort*)(ws + OFF_WFH);
    ushort* WFL   = (ushort*)(ws + OFF_WFL);
    ushort* WOH   = (ushort*)(ws + OFF_WOH);
    ushort* WOL   = (ushort*)(ws + OFF_WOL);
    float*  BWf   = ws + OFF_BWF;
    bf16x8* BWpk  = (bf16x8*)(ws + OFF_BWPK);
    bf16x8* WHpk  = (bf16x8*)(ws + OFF_WHPK);
    float*  Hall  = ws + OFF_HALL;
    int*    start = (int*)(ws + OFF_START);
    int2*   sortedE2 = (int2*)(ws + OFF_SE);
    float*  inv_nv= ws + OFF_INV;
    float*  GI    = ws + OFF_GI;
    ushort* Ub    = (ushort*)(ws + OFF_UB);

    // L1: prep + packs + inv_nv + zero(gout) + per-chunk packed bin-sort
    k_front<<<626, 256, 0, stream>>>(obj_emb, c1_W, c1_b, state_W, state_b,
                                     c2_W, c2_b, o_wih, o_whh, g_wih, g_bih, g_bhh,
                                     visibility, edges, edge_types, mask_edges,
                                     pre1, QT, bQ, bfold, WiT, bI, bH,
                                     WFH, WFL, WOH, WOL, inv_nv, gout,
                                     start, sortedE2);
    // L2: BW_f32 + GI (MFMA)
    k_mid<<<1270, 448, 0, stream>>>(edge_embed, WiT, BWf, class_names, states,
                                    pre1, QT, bQ, bfold,
                                    (const bf16x8*)WFH, (const bf16x8*)WFL, GI);
    // L3: outer GRU (MFMA) + bf16 pack
    k_mid2<<<208, 448, 0, stream>>>(GI, (const bf16x8*)WOH, (const bf16x8*)WOL,
                                    Hall, BWf, g_whh, BWpk, WHpk);
    // L4: gather, one wave per row -> Ub (bf16)
    k_gather<<<NROW / 4, 256, 0, stream>>>(start, sortedE2, Hall, (unsigned*)Ub);
    // L5: fused inner GRU + visibility mask + global mean
    k_fused32<<<NROW / 32, 448, 0, stream>>>(Ub, BWpk, WHpk, bI, bH, Hall,
                                             visibility, inv_nv, out, gout);
}